// Round 15
// baseline (82.631 us; speedup 1.0000x reference)
//
#include <hip/hip_runtime.h>
#include <hip/hip_bf16.h>

// Problem constants
#define B_    16
#define T_    2048
#define H_    512
#define BT_   32768      // B*T tokens
#define DIN   80         // obs 64 + act 16
#define L_    64
#define C_    32
#define O_    64
#define NCHUNK (BT_ / L_)  // 512 chunks

typedef __attribute__((ext_vector_type(8))) short short8;
typedef __attribute__((ext_vector_type(4))) float f32x4;
typedef __attribute__((ext_vector_type(4))) float float4v;

__device__ __forceinline__ float bf2f(unsigned short u) {
  union { unsigned int i; float f; } x; x.i = ((unsigned int)u) << 16; return x.f;
}
__device__ __forceinline__ unsigned short f2bf(float f) {
  union { float f; unsigned int i; } x; x.f = f;
  unsigned int r = x.i + 0x7fffu + ((x.i >> 16) & 1u);
  return (unsigned short)(r >> 16);
}

#define WEP   96                     // padded W_e K (80 -> 96)
#define WE_N  (H_ * WEP)             // 49152
#define WB_N  (H_ * H_)              // 262144
#define WO_N  (O_ * H_)              // 32768
#define PW_N  (WE_N + WB_N + WO_N + H_)   // 344576 = 1346 * 256

// ---------------------------------------------------------------------------
// Kernel 1: weight prep. Web [512][96] bf16 (zero-padded), WBb, Woutb bf16,
// aarr = tanh(a_raw), powa[i][h] = a^(i+1) (i 0..15).
// ---------------------------------------------------------------------------
__global__ __launch_bounds__(256) void prep_w(
    const float* __restrict__ W_e, const float* __restrict__ W_B,
    const float* __restrict__ W_out, const float* __restrict__ a_raw,
    unsigned short* __restrict__ Web, unsigned short* __restrict__ WBb,
    unsigned short* __restrict__ Woutb, float* __restrict__ aarr,
    float* __restrict__ powa)
{
  const int idx = blockIdx.x * 256 + threadIdx.x;
  if (idx < WE_N) {
    const int h = idx / WEP, d = idx % WEP;
    Web[idx] = (d < DIN) ? f2bf(W_e[h * DIN + d]) : (unsigned short)0;
  } else if (idx < WE_N + WB_N) {
    const int j2 = idx - WE_N;
    WBb[j2] = f2bf(W_B[j2]);
  } else if (idx < WE_N + WB_N + WO_N) {
    const int j2 = idx - (WE_N + WB_N);
    Woutb[j2] = f2bf(W_out[j2]);
  } else if (idx < PW_N) {
    const int h = idx - (WE_N + WB_N + WO_N);
    const float a = tanhf(a_raw[h]);
    aarr[h] = a;
    float p = a;
    #pragma unroll
    for (int i = 0; i < 16; ++i) { powa[i * H_ + h] = p; p *= a; }
  }
}

// ---------------------------------------------------------------------------
// Kernel 2: FUSED embed + B-projection. 256 blocks x 512 threads (8 waves
// 2M x 4N), block = (mt: 256 tokens, nt: 256 v-cols). No u round-trip:
// per K-tile q, the A-tile u[256][64] (u-cols k0..k0+63) is computed
// IN-BLOCK from the LDS-staged x-tile and L2-hot Web fragments, written
// (relu+bias, bf16, XOR-swizzled) into an A double-buffer, then consumed
// by the main MFMA (WB frags straight from per-XCD L2 into regs — 20
// independent 16B loads per wave per tile, issued a phase before use).
// LDS: xb [256][128] bf16 swizzled (64KB) + A dbuf 2x32KB = 128KB.
// One __syncthreads per K-tile: embed(q+1)->buf[(q+1)&1] runs concurrent
// with main(q)<-buf[q&1]; the barrier orders buffer reuse both ways.
// Epilogues (v bf16 write + chunk-end e Horner) identical to R12.
// ---------------------------------------------------------------------------
__global__ __launch_bounds__(512) void fused_eb(
    const float* __restrict__ obs, const float* __restrict__ act,
    const unsigned short* __restrict__ Web,   // [512][96] bf16
    const float* __restrict__ b_e,
    const unsigned short* __restrict__ WBb,   // [512][512] bf16
    const float* __restrict__ powa,
    unsigned short* __restrict__ v, float* __restrict__ e)
{
  __shared__ __align__(16) unsigned char lds[131072];

  const int tid  = threadIdx.x;
  const int lane = tid & 63;
  const int wid  = tid >> 6;
  const int wr   = wid >> 2;          // 0..1 (M, main)
  const int wc   = wid & 3;           // 0..3 (N, main)
  const int cl   = lane & 15;
  const int kgrp = lane >> 4;
  const int rg   = kgrp * 4;

  const int X  = (int)blockIdx.x & 7;
  const int j  = (int)blockIdx.x >> 3;
  const int mt = X * 16 + (j >> 1);
  const int nt = j & 1;
  const int row0 = mt * 256, col0 = nt * 256;

  // ---- stage x-tile [256][128] bf16, swizzle c16 ^= row&15 ----
  {
    const int row  = tid >> 1;
    const int half = tid & 1;
    {
      const float4v* src = (const float4v*)(obs + (size_t)(row0 + row) * 64 + half * 32);
      float f[32];
      #pragma unroll
      for (int i = 0; i < 8; ++i) {
        const float4v t4 = src[i];
        f[i*4+0]=t4[0]; f[i*4+1]=t4[1]; f[i*4+2]=t4[2]; f[i*4+3]=t4[3];
      }
      #pragma unroll
      for (int cc = 0; cc < 4; ++cc) {
        short8 o8;
        #pragma unroll
        for (int jj = 0; jj < 8; ++jj) o8[jj] = (short)f2bf(f[cc*8+jj]);
        const int c16 = half * 4 + cc;
        *(short8*)(lds + row * 256 + ((c16 ^ (row & 15)) << 4)) = o8;
      }
    }
    if (half == 0) {        // act -> c16 8,9 ; zeros -> c16 10,11
      const float4v* asrc = (const float4v*)(act + (size_t)(row0 + row) * 16);
      float g2[16];
      #pragma unroll
      for (int i = 0; i < 4; ++i) {
        const float4v t4 = asrc[i];
        g2[i*4+0]=t4[0]; g2[i*4+1]=t4[1]; g2[i*4+2]=t4[2]; g2[i*4+3]=t4[3];
      }
      #pragma unroll
      for (int cc = 0; cc < 2; ++cc) {
        short8 o8;
        #pragma unroll
        for (int jj = 0; jj < 8; ++jj) o8[jj] = (short)f2bf(g2[cc*8+jj]);
        *(short8*)(lds + row * 256 + (((8 + cc) ^ (row & 15)) << 4)) = o8;
      }
      short8 z8;
      #pragma unroll
      for (int jj = 0; jj < 8; ++jj) z8[jj] = 0;
      #pragma unroll
      for (int cc = 2; cc < 4; ++cc)
        *(short8*)(lds + row * 256 + (((8 + cc) ^ (row & 15)) << 4)) = z8;
    }
    // c16 12..15 never read (embed kx < 96): left unwritten.
  }
  __syncthreads();

  // ---- embed phase: A-tile u[256][k0..k0+63] -> A-buf[buf] ----
  // Wave wid owns token rows wid*32..+31 (2 mF x 4 nF frags, kx = 3x32).
  auto embed_phase = [&](int q, int buf) {
    const int k0 = q * 64;
    short8 wb[4][3];
    #pragma unroll
    for (int nF = 0; nF < 4; ++nF) {
      const int h = k0 + nF * 16 + cl;
      #pragma unroll
      for (int kxs = 0; kxs < 3; ++kxs)
        wb[nF][kxs] = *(const short8*)(Web + (size_t)h * WEP + kxs * 32 + kgrp * 8);
    }
    short8 xa[2][3];
    #pragma unroll
    for (int mF = 0; mF < 2; ++mF) {
      const int row = (wid << 5) + mF * 16 + cl;
      #pragma unroll
      for (int kxs = 0; kxs < 3; ++kxs) {
        const int c16 = kxs * 4 + kgrp;
        xa[mF][kxs] = *(const short8*)(lds + row * 256 + ((c16 ^ (row & 15)) << 4));
      }
    }
    f32x4 ea[2][4];
    #pragma unroll
    for (int mF = 0; mF < 2; ++mF)
      #pragma unroll
      for (int nF = 0; nF < 4; ++nF) ea[mF][nF] = f32x4{0.f, 0.f, 0.f, 0.f};
    #pragma unroll
    for (int kxs = 0; kxs < 3; ++kxs)
      #pragma unroll
      for (int mF = 0; mF < 2; ++mF)
        #pragma unroll
        for (int nF = 0; nF < 4; ++nF)
          ea[mF][nF] = __builtin_amdgcn_mfma_f32_16x16x32_bf16(
              xa[mF][kxs], wb[nF][kxs], ea[mF][nF], 0, 0, 0);
    // relu + bias -> bf16 -> swizzled A-buf [256][64] (c16 = colL>>3)
    unsigned char* abuf = lds + 65536 + buf * 32768;
    #pragma unroll
    for (int nF = 0; nF < 4; ++nF) {
      const int colL = nF * 16 + cl;
      const float be = b_e[k0 + colL];
      const int c16 = colL >> 3;
      const int cb  = (colL & 7) * 2;
      #pragma unroll
      for (int mF = 0; mF < 2; ++mF) {
        #pragma unroll
        for (int e2 = 0; e2 < 4; ++e2) {
          const int row = (wid << 5) + mF * 16 + rg + e2;
          const float uu = fmaxf(ea[mF][nF][e2] + be, 0.f);
          *(unsigned short*)(abuf + row * 128 + ((c16 ^ (row & 7)) << 4) + cb) = f2bf(uu);
        }
      }
    }
  };

  f32x4 acc[8][4];
  #pragma unroll
  for (int m = 0; m < 8; ++m)
    #pragma unroll
    for (int n = 0; n < 4; ++n) acc[m][n] = f32x4{0.f, 0.f, 0.f, 0.f};

  embed_phase(0, 0);
  __syncthreads();

  for (int q = 0; q < 8; ++q) {
    if (q + 1 < 8) embed_phase(q + 1, (q + 1) & 1);   // fills other buffer

    // main(q): WB frags from L2 -> regs; af from A-buf[q&1]
    const unsigned char* bufp = lds + 65536 + (q & 1) * 32768;
    short8 bfr[4][2];
    #pragma unroll
    for (int nF = 0; nF < 4; ++nF) {
      const int col = col0 + wc * 64 + nF * 16 + cl;
      #pragma unroll
      for (int ks = 0; ks < 2; ++ks)
        bfr[nF][ks] = *(const short8*)(WBb + (size_t)col * H_ + q * 64 + ks * 32 + kgrp * 8);
    }
    __builtin_amdgcn_s_setprio(1);
    #pragma unroll
    for (int g = 0; g < 4; ++g) {
      short8 af[2][2];
      #pragma unroll
      for (int mm = 0; mm < 2; ++mm) {
        const int row = wr * 128 + (g * 2 + mm) * 16 + cl;
        #pragma unroll
        for (int ks = 0; ks < 2; ++ks)
          af[mm][ks] = *(const short8*)(bufp + row * 128 +
                                        ((((ks << 2) + kgrp) ^ (row & 7)) << 4));
      }
      #pragma unroll
      for (int ks = 0; ks < 2; ++ks)
        #pragma unroll
        for (int mm = 0; mm < 2; ++mm)
          #pragma unroll
          for (int n = 0; n < 4; ++n)
            acc[g * 2 + mm][n] = __builtin_amdgcn_mfma_f32_16x16x32_bf16(
                af[mm][ks], bfr[n][ks], acc[g * 2 + mm][n], 0, 0, 0);
    }
    __builtin_amdgcn_s_setprio(0);
    __syncthreads();   // buf[(q+1)&1] ready for main(q+1); buf[q&1] free
  }

  // Epilogue: v write. D[r][c]: c = lane&15, r = (lane>>4)*4 + e2
  #pragma unroll
  for (int m = 0; m < 8; ++m) {
    #pragma unroll
    for (int n = 0; n < 4; ++n) {
      const int gc = col0 + wc * 64 + n * 16 + cl;
      #pragma unroll
      for (int e2 = 0; e2 < 4; ++e2) {
        const int gr = row0 + wr * 128 + m * 16 + rg + e2;
        v[(size_t)gr * H_ + gc] = f2bf(acc[m][n][e2]);
      }
    }
  }

  // Chunk-end e: wave spans 2 chunks (m 0..3, m 4..7).
  #pragma unroll
  for (int c = 0; c < 2; ++c) {
    const int chunk = ((row0 + wr * 128) >> 6) + c;
    #pragma unroll
    for (int n = 0; n < 4; ++n) {
      const int h = col0 + wc * 64 + n * 16 + cl;
      const float a16 = powa[15 * H_ + h];
      float ep = 0.f;
      #pragma unroll
      for (int e2 = 0; e2 < 4; ++e2) {
        const int k = 15 - rg - e2;
        const float wk = (k == 0) ? 1.f : powa[(size_t)(k - 1) * H_ + h];
        float hsum = acc[c * 4 + 0][n][e2];
        hsum = fmaf(hsum, a16, acc[c * 4 + 1][n][e2]);
        hsum = fmaf(hsum, a16, acc[c * 4 + 2][n][e2]);
        hsum = fmaf(hsum, a16, acc[c * 4 + 3][n][e2]);
        ep = fmaf(wk, hsum, ep);
      }
      ep += __shfl_xor(ep, 16);
      ep += __shfl_xor(ep, 32);
      if (kgrp == 0)
        e[(size_t)chunk * H_ + h] = ep;
    }
  }
}

// ---------------------------------------------------------------------------
// Kernel 3: fused carry + scan + out-projection (R12-proven, unchanged;
// chunk map matches producer XCDs: chunk = (bid&7)*64 + bid>>3).
// ---------------------------------------------------------------------------
__global__ __launch_bounds__(256) void scan_out(
    const unsigned int* __restrict__ v, const float* __restrict__ e,
    const float* __restrict__ aarr, const unsigned short* __restrict__ Wo,
    const float* __restrict__ b_out, float* __restrict__ y)
{
  __shared__ __align__(16) unsigned char sbytes[64 * 1024];
  const int blk = ((int)blockIdx.x & 7) * 64 + ((int)blockIdx.x >> 3);
  const int b = blk >> 5, c = blk & 31;
  const int tid = threadIdx.x;
  const int lane = tid & 63, w = tid >> 6;
  const int row_base = blk * L_;

  {
    const int h0 = tid * 2;
    const float a0 = aarr[h0], a1 = aarr[h0 + 1];
    float aL0 = a0 * a0, aL1 = a1 * a1;
    aL0 *= aL0; aL1 *= aL1;
    aL0 *= aL0; aL1 *= aL1;
    aL0 *= aL0; aL1 *= aL1;
    aL0 *= aL0; aL1 *= aL1;
    aL0 *= aL0; aL1 *= aL1;                       // a^64
    float s0 = 0.f, s1 = 0.f;
    #pragma unroll
    for (int g = 0; g < 4; ++g) {
      float ev0[8], ev1[8];
      #pragma unroll
      for (int k = 0; k < 8; ++k) {
        const size_t o = ((size_t)(b * C_ + g * 8 + k)) * H_ + h0;
        ev0[k] = e[o]; ev1[k] = e[o + 1];
      }
      #pragma unroll
      for (int k = 0; k < 8; ++k) {
        const bool pred = (g * 8 + k) < c;
        s0 = pred ? fmaf(aL0, s0, ev0[k]) : s0;
        s1 = pred ? fmaf(aL1, s1, ev1[k]) : s1;
      }
    }
    const unsigned int* vp = v + (size_t)row_base * (H_ / 2) + tid;
    #pragma unroll 8
    for (int t = 0; t < L_; ++t) {
      const unsigned int pv = vp[(size_t)t * (H_ / 2)];
      s0 = fmaf(a0, s0, bf2f((unsigned short)(pv & 0xffff)));
      s1 = fmaf(a1, s1, bf2f((unsigned short)(pv >> 16)));
      const int byte = t * 1024 + ((tid * 4) ^ ((t & 7) << 4));
      *(unsigned int*)(sbytes + byte) =
          (unsigned int)f2bf(s0) | ((unsigned int)f2bf(s1) << 16);
    }
  }
  __syncthreads();

  f32x4 acc[4];
  #pragma unroll
  for (int n = 0; n < 4; ++n) acc[n] = f32x4{0.f, 0.f, 0.f, 0.f};
  const int r = w * 16 + (lane & 15);
  const int kof = (lane >> 4) * 8;
  #pragma unroll 4
  for (int k0 = 0; k0 < H_; k0 += 32) {
    const int byte = r * 1024 + (((k0 + kof) * 2) ^ ((r & 7) << 4));
    const short8 af = *(const short8*)(sbytes + byte);
    #pragma unroll
    for (int n = 0; n < 4; ++n) {
      const short8 bf = *(const short8*)(Wo + (size_t)(n * 16 + (lane & 15)) * H_ + k0 + kof);
      acc[n] = __builtin_amdgcn_mfma_f32_16x16x32_bf16(af, bf, acc[n], 0, 0, 0);
    }
  }
  const int cl = lane & 15, rg = (lane >> 4) * 4;
  #pragma unroll
  for (int n = 0; n < 4; ++n) {
    #pragma unroll
    for (int e2 = 0; e2 < 4; ++e2) {
      const int gr = row_base + w * 16 + rg + e2;
      const int gc = n * 16 + cl;
      y[(size_t)gr * O_ + gc] = acc[n][e2] + b_out[gc];
    }
  }
}

// ---------------------------------------------------------------------------
extern "C" void kernel_launch(void* const* d_in, const int* in_sizes, int n_in,
                              void* d_out, int out_size, void* d_ws, size_t ws_size,
                              hipStream_t stream)
{
  const float* obs   = (const float*)d_in[0];
  const float* act   = (const float*)d_in[1];
  const float* W_e   = (const float*)d_in[2];
  const float* b_e   = (const float*)d_in[3];
  const float* a_raw = (const float*)d_in[4];
  const float* W_B   = (const float*)d_in[5];
  const float* W_out = (const float*)d_in[6];
  const float* b_out = (const float*)d_in[7];
  float* y = (float*)d_out;

  char* w = (char*)d_ws;
  auto carve = [&](size_t bytes) {
    char* p = w; w += (bytes + 255) & ~(size_t)255; return p;
  };
  unsigned short* Web   = (unsigned short*)carve((size_t)H_ * WEP * 2);
  unsigned short* WBb   = (unsigned short*)carve((size_t)H_ * H_ * 2);
  unsigned short* Woutb = (unsigned short*)carve((size_t)O_ * H_ * 2);
  float*          aarr  = (float*)carve((size_t)H_ * 4);
  float*          powa  = (float*)carve((size_t)16 * H_ * 4);
  unsigned short* v     = (unsigned short*)carve((size_t)BT_ * H_ * 2);   // 33.5 MB
  float*          e     = (float*)carve((size_t)NCHUNK * H_ * 4);         // 1 MB

  // 1) weight prep (Web padded bf16, WBb, Woutb, tanh + power table)
  prep_w<<<PW_N / 256, 256, 0, stream>>>(W_e, W_B, W_out, a_raw,
                                         Web, WBb, Woutb, aarr, powa);
  // 2) fused embed + B-projection -> v, e (no u buffer at all)
  fused_eb<<<256, 512, 0, stream>>>(obs, act, Web, b_e, WBb, powa, v, e);
  // 3) fused carry + scan + out-projection -> y
  scan_out<<<NCHUNK, 256, 0, stream>>>((const unsigned int*)v, e, aarr,
                                       Woutb, b_out, y);
}

// Round 16
// 69.568 us; speedup vs baseline: 1.1878x; 1.1878x over previous
//
#include <hip/hip_runtime.h>
#include <hip/hip_bf16.h>

// Problem constants
#define B_    16
#define T_    2048
#define H_    512
#define BT_   32768      // B*T tokens
#define DIN   80         // obs 64 + act 16
#define L_    64
#define C_    32
#define O_    64
#define NCHUNK (BT_ / L_)  // 512 chunks

typedef __attribute__((ext_vector_type(8))) short short8;
typedef __attribute__((ext_vector_type(4))) float f32x4;
typedef __attribute__((ext_vector_type(4))) float float4v;

__device__ __forceinline__ float bf2f(unsigned short u) {
  union { unsigned int i; float f; } x; x.i = ((unsigned int)u) << 16; return x.f;
}
__device__ __forceinline__ unsigned short f2bf(float f) {
  union { float f; unsigned int i; } x; x.f = f;
  unsigned int r = x.i + 0x7fffu + ((x.i >> 16) & 1u);
  return (unsigned short)(r >> 16);
}

#define WB_N  (H_ * H_)
#define WO_N  (O_ * H_)

// ---------------------------------------------------------------------------
// Kernel 1: embed GEMM with inline prep (R9/R12-proven, unchanged).
// u = relu(concat(obs,act) @ We^T + b_e); prologue preps WBb/Woutb/aarr/powa.
// ---------------------------------------------------------------------------
__global__ __launch_bounds__(512) void embed_gemm(
    const float* __restrict__ obs, const float* __restrict__ act,
    const float* __restrict__ W_e, const float* __restrict__ b_e,
    const float* __restrict__ a_raw, const float* __restrict__ W_B,
    const float* __restrict__ W_out,
    unsigned short* __restrict__ WBb, unsigned short* __restrict__ Woutb,
    float* __restrict__ aarr, float* __restrict__ powa,
    unsigned short* __restrict__ u)
{
  __shared__ __align__(16) unsigned char lds[131072];

  const int tid  = threadIdx.x;
  const int lane = tid & 63;
  const int wid  = tid >> 6;
  const int wr   = wid >> 2;
  const int wc   = wid & 3;
  const int cl   = lane & 15;
  const int kgrp = lane >> 4;
  const int rg   = kgrp * 4;

  const int X  = (int)blockIdx.x & 7;
  const int j  = (int)blockIdx.x >> 3;
  const int mt = X * 16 + (j >> 1);
  const int nt = j & 1;
  const int row0 = mt * 256, col0 = nt * 256;

  // Prologue: strided prep
  {
    const int g = (int)blockIdx.x * 512 + tid;
    #pragma unroll
    for (int r = 0; r < 2; ++r) {
      const int idx = g * 2 + r;
      WBb[idx] = f2bf(W_B[idx]);
    }
    if (g < WO_N) Woutb[g] = f2bf(W_out[g]);
    if (g < H_) {
      const float a = tanhf(a_raw[g]);
      aarr[g] = a;
      float p = a;
      #pragma unroll
      for (int i = 0; i < 16; ++i) { powa[i * H_ + g] = p; p *= a; }
    }
  }

  // A-tiles: inline f32->bf16, swizzled ds_write
  {
    const int row  = tid >> 1;
    const int half = tid & 1;
    {
      const float4v* src = (const float4v*)(obs + (size_t)(row0 + row) * 64 + half * 32);
      float f[32];
      #pragma unroll
      for (int i = 0; i < 8; ++i) {
        const float4v t4 = src[i];
        f[i*4+0]=t4[0]; f[i*4+1]=t4[1]; f[i*4+2]=t4[2]; f[i*4+3]=t4[3];
      }
      #pragma unroll
      for (int cc = 0; cc < 4; ++cc) {
        short8 o8;
        #pragma unroll
        for (int jj = 0; jj < 8; ++jj) o8[jj] = (short)f2bf(f[cc*8+jj]);
        const int c16 = half * 4 + cc;
        *(short8*)(lds + row * 128 + ((c16 ^ (row & 7)) << 4)) = o8;
      }
    }
    {
      short8 z8;
      #pragma unroll
      for (int jj = 0; jj < 8; ++jj) z8[jj] = 0;
      if (half == 0) {
        const float4v* asrc = (const float4v*)(act + (size_t)(row0 + row) * 16);
        float g2[16];
        #pragma unroll
        for (int i = 0; i < 4; ++i) {
          const float4v t4 = asrc[i];
          g2[i*4+0]=t4[0]; g2[i*4+1]=t4[1]; g2[i*4+2]=t4[2]; g2[i*4+3]=t4[3];
        }
        #pragma unroll
        for (int cc = 0; cc < 2; ++cc) {
          short8 o8;
          #pragma unroll
          for (int jj = 0; jj < 8; ++jj) o8[jj] = (short)f2bf(g2[cc*8+jj]);
          *(short8*)(lds + 65536 + row * 128 + ((cc ^ (row & 7)) << 4)) = o8;
        }
        #pragma unroll
        for (int cc = 2; cc < 4; ++cc)
          *(short8*)(lds + 65536 + row * 128 + ((cc ^ (row & 7)) << 4)) = z8;
      } else {
        #pragma unroll
        for (int cc = 4; cc < 8; ++cc)
          *(short8*)(lds + 65536 + row * 128 + ((cc ^ (row & 7)) << 4)) = z8;
      }
    }
  }
  // B-tiles: W_e inline f32->bf16
  {
    const int colL = tid >> 1;
    const int col  = col0 + colL;
    const int half = tid & 1;
    {
      const float4v* src = (const float4v*)(W_e + (size_t)col * DIN + half * 32);
      float f[32];
      #pragma unroll
      for (int i = 0; i < 8; ++i) {
        const float4v t4 = src[i];
        f[i*4+0]=t4[0]; f[i*4+1]=t4[1]; f[i*4+2]=t4[2]; f[i*4+3]=t4[3];
      }
      #pragma unroll
      for (int cc = 0; cc < 4; ++cc) {
        short8 o8;
        #pragma unroll
        for (int jj = 0; jj < 8; ++jj) o8[jj] = (short)f2bf(f[cc*8+jj]);
        const int c16 = half * 4 + cc;
        *(short8*)(lds + 32768 + colL * 128 + ((c16 ^ (colL & 7)) << 4)) = o8;
      }
    }
    {
      short8 z8;
      #pragma unroll
      for (int jj = 0; jj < 8; ++jj) z8[jj] = 0;
      if (half == 0) {
        const float4v* src = (const float4v*)(W_e + (size_t)col * DIN + 64);
        float g2[16];
        #pragma unroll
        for (int i = 0; i < 4; ++i) {
          const float4v t4 = src[i];
          g2[i*4+0]=t4[0]; g2[i*4+1]=t4[1]; g2[i*4+2]=t4[2]; g2[i*4+3]=t4[3];
        }
        #pragma unroll
        for (int cc = 0; cc < 2; ++cc) {
          short8 o8;
          #pragma unroll
          for (int jj = 0; jj < 8; ++jj) o8[jj] = (short)f2bf(g2[cc*8+jj]);
          *(short8*)(lds + 98304 + colL * 128 + ((cc ^ (colL & 7)) << 4)) = o8;
        }
        #pragma unroll
        for (int cc = 2; cc < 4; ++cc)
          *(short8*)(lds + 98304 + colL * 128 + ((cc ^ (colL & 7)) << 4)) = z8;
      } else {
        #pragma unroll
        for (int cc = 4; cc < 8; ++cc)
          *(short8*)(lds + 98304 + colL * 128 + ((cc ^ (colL & 7)) << 4)) = z8;
      }
    }
  }
  __syncthreads();

  f32x4 acc[8][4];
  #pragma unroll
  for (int m = 0; m < 8; ++m)
    #pragma unroll
    for (int n = 0; n < 4; ++n) acc[m][n] = f32x4{0.f, 0.f, 0.f, 0.f};

  #pragma unroll
  for (int q = 0; q < 2; ++q) {
    const unsigned char* bufp = lds + q * 65536;
    short8 bfr[4][2];
    #pragma unroll
    for (int n = 0; n < 4; ++n) {
      const int col = wc * 64 + n * 16 + cl;
      #pragma unroll
      for (int ks = 0; ks < 2; ++ks)
        bfr[n][ks] = *(const short8*)(bufp + 32768 + col * 128 +
                                      ((((ks << 2) + kgrp) ^ (col & 7)) << 4));
    }
    #pragma unroll
    for (int g = 0; g < 4; ++g) {
      short8 af[2][2];
      #pragma unroll
      for (int mm = 0; mm < 2; ++mm) {
        const int row = wr * 128 + (g * 2 + mm) * 16 + cl;
        #pragma unroll
        for (int ks = 0; ks < 2; ++ks)
          af[mm][ks] = *(const short8*)(bufp + row * 128 +
                                        ((((ks << 2) + kgrp) ^ (row & 7)) << 4));
      }
      #pragma unroll
      for (int ks = 0; ks < 2; ++ks)
        #pragma unroll
        for (int mm = 0; mm < 2; ++mm)
          #pragma unroll
          for (int n = 0; n < 4; ++n)
            acc[g * 2 + mm][n] = __builtin_amdgcn_mfma_f32_16x16x32_bf16(
                af[mm][ks], bfr[n][ks], acc[g * 2 + mm][n], 0, 0, 0);
    }
  }

  #pragma unroll
  for (int m = 0; m < 8; ++m) {
    #pragma unroll
    for (int n = 0; n < 4; ++n) {
      const int gc = col0 + wc * 64 + n * 16 + cl;
      const float be = b_e[gc];
      #pragma unroll
      for (int e2 = 0; e2 < 4; ++e2) {
        const int gr = row0 + wr * 128 + m * 16 + rg + e2;
        u[(size_t)gr * H_ + gc] = f2bf(fmaxf(acc[m][n][e2] + be, 0.f));
      }
    }
  }
}

// ---------------------------------------------------------------------------
// Kernel 2: B-projection GEMM (R9/R12-proven 256x256 counted-vmcnt).
// One change vs R12: CE-epilogue powa/a16 values preloaded into registers
// BEFORE the K-loop (their L2 latency hides under the prologue staging
// wait, instead of serializing after the last MFMA).
// ---------------------------------------------------------------------------
__global__ __launch_bounds__(512) void gemm_bproj(
    const unsigned short* __restrict__ A, const unsigned short* __restrict__ Bt,
    unsigned short* __restrict__ Cb,
    const float* __restrict__ powa, float* __restrict__ e)
{
  constexpr int NT = 8;
  __shared__ __align__(16) unsigned char lds[131072];

  const int tid  = threadIdx.x;
  const int lane = tid & 63;
  const int wid  = tid >> 6;
  const int wr   = wid >> 2;
  const int wc   = wid & 3;
  const int cl   = lane & 15;
  const int kgrp = lane >> 4;
  const int rg   = kgrp * 4;

  const int X  = (int)blockIdx.x & 7;
  const int j  = (int)blockIdx.x >> 3;
  const int mt = X * 16 + (j >> 1);
  const int nt = j & 1;
  const int row0 = mt * 256, col0 = nt * 256;

  auto stageA = [&](int q, int buf) {
    const int k0 = q * 64;
    #pragma unroll
    for (int r = 0; r < 4; ++r) {
      const int o   = r * 8192 + tid * 16;
      const int row = o >> 7;
      const int c16 = (o >> 4) & 7;
      const int kk  = (c16 ^ (row & 7)) << 3;
      __builtin_amdgcn_global_load_lds(
          (const __attribute__((address_space(1))) void*)
              (A + (size_t)(row0 + row) * H_ + k0 + kk),
          (__attribute__((address_space(3))) void*)(lds + buf * 65536 + o),
          16, 0, 0);
    }
  };
  auto stageB_round = [&](int q, int buf, int r) {
    const int k0 = q * 64;
    const int o   = r * 8192 + tid * 16;
    const int col = o >> 7;
    const int c16 = (o >> 4) & 7;
    const int kk  = (c16 ^ (col & 7)) << 3;
    __builtin_amdgcn_global_load_lds(
        (const __attribute__((address_space(1))) void*)
            (Bt + (size_t)(col0 + col) * H_ + k0 + kk),
        (__attribute__((address_space(3))) void*)(lds + buf * 65536 + 32768 + o),
        16, 0, 0);
  };

  f32x4 acc[8][4];
  #pragma unroll
  for (int m = 0; m < 8; ++m)
    #pragma unroll
    for (int n = 0; n < 4; ++n) acc[m][n] = f32x4{0.f, 0.f, 0.f, 0.f};

  stageA(0, 0);
  #pragma unroll
  for (int r = 0; r < 4; ++r) stageB_round(0, 0, r);
  #pragma unroll
  for (int r = 0; r < 4; ++r) stageB_round(1, 1, r);

  // CE-epilogue constant preload (latency hidden under the staging wait):
  // per n: a16 = a^16 and wk[e2] = a^{15-rg-e2} (k==0 -> 1.0) for h(n).
  float a16r[4], wkr[4][4];
  #pragma unroll
  for (int n = 0; n < 4; ++n) {
    const int h = col0 + wc * 64 + n * 16 + cl;
    a16r[n] = powa[15 * H_ + h];
    #pragma unroll
    for (int e2 = 0; e2 < 4; ++e2) {
      const int k = 15 - rg - e2;
      wkr[n][e2] = (k == 0) ? 1.f : powa[(size_t)(k - 1) * H_ + h];
    }
  }

  asm volatile("s_waitcnt vmcnt(4)" ::: "memory");
  __builtin_amdgcn_sched_barrier(0);
  __builtin_amdgcn_s_barrier();

  for (int q = 0; q < NT; ++q) {
    const int cur = q & 1;
    const unsigned char* bufp = lds + cur * 65536;

    if (q + 1 < NT) stageA(q + 1, cur ^ 1);

    short8 bfr[4][2];
    #pragma unroll
    for (int n = 0; n < 4; ++n) {
      const int col = wc * 64 + n * 16 + cl;
      #pragma unroll
      for (int ks = 0; ks < 2; ++ks)
        bfr[n][ks] = *(const short8*)(bufp + 32768 + col * 128 +
                                      ((((ks << 2) + kgrp) ^ (col & 7)) << 4));
    }
    asm volatile("s_waitcnt lgkmcnt(0)" ::: "memory");
    __builtin_amdgcn_sched_barrier(0);
    __builtin_amdgcn_s_barrier();

    __builtin_amdgcn_s_setprio(1);
    #pragma unroll
    for (int g = 0; g < 4; ++g) {
      if (q + 2 < NT) stageB_round(q + 2, cur, g);
      short8 af[2][2];
      #pragma unroll
      for (int mm = 0; mm < 2; ++mm) {
        const int row = wr * 128 + (g * 2 + mm) * 16 + cl;
        #pragma unroll
        for (int ks = 0; ks < 2; ++ks)
          af[mm][ks] = *(const short8*)(bufp + row * 128 +
                                        ((((ks << 2) + kgrp) ^ (row & 7)) << 4));
      }
      #pragma unroll
      for (int ks = 0; ks < 2; ++ks)
        #pragma unroll
        for (int mm = 0; mm < 2; ++mm)
          #pragma unroll
          for (int n = 0; n < 4; ++n)
            acc[g * 2 + mm][n] = __builtin_amdgcn_mfma_f32_16x16x32_bf16(
                af[mm][ks], bfr[n][ks], acc[g * 2 + mm][n], 0, 0, 0);
    }
    __builtin_amdgcn_s_setprio(0);

    if (q + 2 < NT) {
      asm volatile("s_waitcnt vmcnt(4)" ::: "memory");
    } else if (q + 1 < NT) {
      asm volatile("s_waitcnt vmcnt(0)" ::: "memory");
    }
    __builtin_amdgcn_sched_barrier(0);
    __builtin_amdgcn_s_barrier();
  }

  #pragma unroll
  for (int m = 0; m < 8; ++m) {
    #pragma unroll
    for (int n = 0; n < 4; ++n) {
      const int gc = col0 + wc * 64 + n * 16 + cl;
      #pragma unroll
      for (int e2 = 0; e2 < 4; ++e2) {
        const int gr = row0 + wr * 128 + m * 16 + rg + e2;
        Cb[(size_t)gr * H_ + gc] = f2bf(acc[m][n][e2]);
      }
    }
  }

  // Chunk-end e: wave spans 2 chunks (m 0..3, m 4..7); constants preloaded.
  #pragma unroll
  for (int c = 0; c < 2; ++c) {
    const int chunk = ((row0 + wr * 128) >> 6) + c;
    #pragma unroll
    for (int n = 0; n < 4; ++n) {
      const int h = col0 + wc * 64 + n * 16 + cl;
      const float a16 = a16r[n];
      float ep = 0.f;
      #pragma unroll
      for (int e2 = 0; e2 < 4; ++e2) {
        float hsum = acc[c * 4 + 0][n][e2];
        hsum = fmaf(hsum, a16, acc[c * 4 + 1][n][e2]);
        hsum = fmaf(hsum, a16, acc[c * 4 + 2][n][e2]);
        hsum = fmaf(hsum, a16, acc[c * 4 + 3][n][e2]);
        ep = fmaf(wkr[n][e2], hsum, ep);
      }
      ep += __shfl_xor(ep, 16);
      ep += __shfl_xor(ep, 32);
      if (kgrp == 0)
        e[(size_t)chunk * H_ + h] = ep;
    }
  }
}

// ---------------------------------------------------------------------------
// Kernel 3: fused carry + scan + out-projection (R12-proven, unchanged;
// chunk map matches producer XCDs: chunk = (bid&7)*64 + bid>>3).
// ---------------------------------------------------------------------------
__global__ __launch_bounds__(256) void scan_out(
    const unsigned int* __restrict__ v, const float* __restrict__ e,
    const float* __restrict__ aarr, const unsigned short* __restrict__ Wo,
    const float* __restrict__ b_out, float* __restrict__ y)
{
  __shared__ __align__(16) unsigned char sbytes[64 * 1024];
  const int blk = ((int)blockIdx.x & 7) * 64 + ((int)blockIdx.x >> 3);
  const int b = blk >> 5, c = blk & 31;
  const int tid = threadIdx.x;
  const int lane = tid & 63, w = tid >> 6;
  const int row_base = blk * L_;

  {
    const int h0 = tid * 2;
    const float a0 = aarr[h0], a1 = aarr[h0 + 1];
    float aL0 = a0 * a0, aL1 = a1 * a1;
    aL0 *= aL0; aL1 *= aL1;
    aL0 *= aL0; aL1 *= aL1;
    aL0 *= aL0; aL1 *= aL1;
    aL0 *= aL0; aL1 *= aL1;
    aL0 *= aL0; aL1 *= aL1;                       // a^64
    float s0 = 0.f, s1 = 0.f;
    #pragma unroll
    for (int g = 0; g < 4; ++g) {
      float ev0[8], ev1[8];
      #pragma unroll
      for (int k = 0; k < 8; ++k) {
        const size_t o = ((size_t)(b * C_ + g * 8 + k)) * H_ + h0;
        ev0[k] = e[o]; ev1[k] = e[o + 1];
      }
      #pragma unroll
      for (int k = 0; k < 8; ++k) {
        const bool pred = (g * 8 + k) < c;
        s0 = pred ? fmaf(aL0, s0, ev0[k]) : s0;
        s1 = pred ? fmaf(aL1, s1, ev1[k]) : s1;
      }
    }
    const unsigned int* vp = v + (size_t)row_base * (H_ / 2) + tid;
    #pragma unroll 8
    for (int t = 0; t < L_; ++t) {
      const unsigned int pv = vp[(size_t)t * (H_ / 2)];
      s0 = fmaf(a0, s0, bf2f((unsigned short)(pv & 0xffff)));
      s1 = fmaf(a1, s1, bf2f((unsigned short)(pv >> 16)));
      const int byte = t * 1024 + ((tid * 4) ^ ((t & 7) << 4));
      *(unsigned int*)(sbytes + byte) =
          (unsigned int)f2bf(s0) | ((unsigned int)f2bf(s1) << 16);
    }
  }
  __syncthreads();

  f32x4 acc[4];
  #pragma unroll
  for (int n = 0; n < 4; ++n) acc[n] = f32x4{0.f, 0.f, 0.f, 0.f};
  const int r = w * 16 + (lane & 15);
  const int kof = (lane >> 4) * 8;
  #pragma unroll 4
  for (int k0 = 0; k0 < H_; k0 += 32) {
    const int byte = r * 1024 + (((k0 + kof) * 2) ^ ((r & 7) << 4));
    const short8 af = *(const short8*)(sbytes + byte);
    #pragma unroll
    for (int n = 0; n < 4; ++n) {
      const short8 bf = *(const short8*)(Wo + (size_t)(n * 16 + (lane & 15)) * H_ + k0 + kof);
      acc[n] = __builtin_amdgcn_mfma_f32_16x16x32_bf16(af, bf, acc[n], 0, 0, 0);
    }
  }
  const int cl = lane & 15, rg = (lane >> 4) * 4;
  #pragma unroll
  for (int n = 0; n < 4; ++n) {
    #pragma unroll
    for (int e2 = 0; e2 < 4; ++e2) {
      const int gr = row_base + w * 16 + rg + e2;
      const int gc = n * 16 + cl;
      y[(size_t)gr * O_ + gc] = acc[n][e2] + b_out[gc];
    }
  }
}

// ---------------------------------------------------------------------------
extern "C" void kernel_launch(void* const* d_in, const int* in_sizes, int n_in,
                              void* d_out, int out_size, void* d_ws, size_t ws_size,
                              hipStream_t stream)
{
  const float* obs   = (const float*)d_in[0];
  const float* act   = (const float*)d_in[1];
  const float* W_e   = (const float*)d_in[2];
  const float* b_e   = (const float*)d_in[3];
  const float* a_raw = (const float*)d_in[4];
  const float* W_B   = (const float*)d_in[5];
  const float* W_out = (const float*)d_in[6];
  const float* b_out = (const float*)d_in[7];
  float* y = (float*)d_out;

  char* w = (char*)d_ws;
  auto carve = [&](size_t bytes) {
    char* p = w; w += (bytes + 255) & ~(size_t)255; return p;
  };
  unsigned short* WBb   = (unsigned short*)carve((size_t)H_ * H_ * 2);
  unsigned short* Woutb = (unsigned short*)carve((size_t)O_ * H_ * 2);
  float*          aarr  = (float*)carve((size_t)H_ * 4);
  float*          powa  = (float*)carve((size_t)16 * H_ * 4);
  unsigned short* u     = (unsigned short*)carve((size_t)BT_ * H_ * 2);   // 33.5 MB
  unsigned short* v     = (unsigned short*)carve((size_t)BT_ * H_ * 2);   // 33.5 MB
  float*          e     = (float*)carve((size_t)NCHUNK * H_ * 4);         // 1 MB

  // 1) embed (+ inline weight prep) -> u
  embed_gemm<<<256, 512, 0, stream>>>(obs, act, W_e, b_e, a_raw, W_B, W_out,
                                      WBb, Woutb, aarr, powa, u);
  // 2) v = u @ WB^T (counted-vmcnt pipeline); epilogue emits e
  gemm_bproj<<<256, 512, 0, stream>>>(u, WBb, v, powa, e);
  // 3) fused carry + scan + out-projection -> y
  scan_out<<<NCHUNK, 256, 0, stream>>>((const unsigned int*)v, e, aarr,
                                       Woutb, b_out, y);
}

// Round 17
// 69.304 us; speedup vs baseline: 1.1923x; 1.0038x over previous
//
#include <hip/hip_runtime.h>
#include <hip/hip_bf16.h>

// Problem constants
#define B_    16
#define T_    2048
#define H_    512
#define BT_   32768      // B*T tokens
#define DIN   80         // obs 64 + act 16
#define L_    64
#define C_    32
#define O_    64
#define NCHUNK (BT_ / L_)  // 512 chunks

typedef __attribute__((ext_vector_type(8))) short short8;
typedef __attribute__((ext_vector_type(4))) float f32x4;
typedef __attribute__((ext_vector_type(4))) float float4v;

__device__ __forceinline__ float bf2f(unsigned short u) {
  union { unsigned int i; float f; } x; x.i = ((unsigned int)u) << 16; return x.f;
}
__device__ __forceinline__ unsigned short f2bf(float f) {
  union { float f; unsigned int i; } x; x.f = f;
  unsigned int r = x.i + 0x7fffu + ((x.i >> 16) & 1u);
  return (unsigned short)(r >> 16);
}

#define WB_N  (H_ * H_)
#define WO_N  (O_ * H_)

// ---------------------------------------------------------------------------
// Kernel 1: embed GEMM with inline prep (R9/R12-proven, unchanged).
// ---------------------------------------------------------------------------
__global__ __launch_bounds__(512) void embed_gemm(
    const float* __restrict__ obs, const float* __restrict__ act,
    const float* __restrict__ W_e, const float* __restrict__ b_e,
    const float* __restrict__ a_raw, const float* __restrict__ W_B,
    const float* __restrict__ W_out,
    unsigned short* __restrict__ WBb, unsigned short* __restrict__ Woutb,
    float* __restrict__ aarr, float* __restrict__ powa,
    unsigned short* __restrict__ u)
{
  __shared__ __align__(16) unsigned char lds[131072];

  const int tid  = threadIdx.x;
  const int lane = tid & 63;
  const int wid  = tid >> 6;
  const int wr   = wid >> 2;
  const int wc   = wid & 3;
  const int cl   = lane & 15;
  const int kgrp = lane >> 4;
  const int rg   = kgrp * 4;

  const int X  = (int)blockIdx.x & 7;
  const int j  = (int)blockIdx.x >> 3;
  const int mt = X * 16 + (j >> 1);
  const int nt = j & 1;
  const int row0 = mt * 256, col0 = nt * 256;

  // Prologue: strided prep
  {
    const int g = (int)blockIdx.x * 512 + tid;
    #pragma unroll
    for (int r = 0; r < 2; ++r) {
      const int idx = g * 2 + r;
      WBb[idx] = f2bf(W_B[idx]);
    }
    if (g < WO_N) Woutb[g] = f2bf(W_out[g]);
    if (g < H_) {
      const float a = tanhf(a_raw[g]);
      aarr[g] = a;
      float p = a;
      #pragma unroll
      for (int i = 0; i < 16; ++i) { powa[i * H_ + g] = p; p *= a; }
    }
  }

  // A-tiles: inline f32->bf16, swizzled ds_write
  {
    const int row  = tid >> 1;
    const int half = tid & 1;
    {
      const float4v* src = (const float4v*)(obs + (size_t)(row0 + row) * 64 + half * 32);
      float f[32];
      #pragma unroll
      for (int i = 0; i < 8; ++i) {
        const float4v t4 = src[i];
        f[i*4+0]=t4[0]; f[i*4+1]=t4[1]; f[i*4+2]=t4[2]; f[i*4+3]=t4[3];
      }
      #pragma unroll
      for (int cc = 0; cc < 4; ++cc) {
        short8 o8;
        #pragma unroll
        for (int jj = 0; jj < 8; ++jj) o8[jj] = (short)f2bf(f[cc*8+jj]);
        const int c16 = half * 4 + cc;
        *(short8*)(lds + row * 128 + ((c16 ^ (row & 7)) << 4)) = o8;
      }
    }
    {
      short8 z8;
      #pragma unroll
      for (int jj = 0; jj < 8; ++jj) z8[jj] = 0;
      if (half == 0) {
        const float4v* asrc = (const float4v*)(act + (size_t)(row0 + row) * 16);
        float g2[16];
        #pragma unroll
        for (int i = 0; i < 4; ++i) {
          const float4v t4 = asrc[i];
          g2[i*4+0]=t4[0]; g2[i*4+1]=t4[1]; g2[i*4+2]=t4[2]; g2[i*4+3]=t4[3];
        }
        #pragma unroll
        for (int cc = 0; cc < 2; ++cc) {
          short8 o8;
          #pragma unroll
          for (int jj = 0; jj < 8; ++jj) o8[jj] = (short)f2bf(g2[cc*8+jj]);
          *(short8*)(lds + 65536 + row * 128 + ((cc ^ (row & 7)) << 4)) = o8;
        }
        #pragma unroll
        for (int cc = 2; cc < 4; ++cc)
          *(short8*)(lds + 65536 + row * 128 + ((cc ^ (row & 7)) << 4)) = z8;
      } else {
        #pragma unroll
        for (int cc = 4; cc < 8; ++cc)
          *(short8*)(lds + 65536 + row * 128 + ((cc ^ (row & 7)) << 4)) = z8;
      }
    }
  }
  // B-tiles: W_e inline f32->bf16
  {
    const int colL = tid >> 1;
    const int col  = col0 + colL;
    const int half = tid & 1;
    {
      const float4v* src = (const float4v*)(W_e + (size_t)col * DIN + half * 32);
      float f[32];
      #pragma unroll
      for (int i = 0; i < 8; ++i) {
        const float4v t4 = src[i];
        f[i*4+0]=t4[0]; f[i*4+1]=t4[1]; f[i*4+2]=t4[2]; f[i*4+3]=t4[3];
      }
      #pragma unroll
      for (int cc = 0; cc < 4; ++cc) {
        short8 o8;
        #pragma unroll
        for (int jj = 0; jj < 8; ++jj) o8[jj] = (short)f2bf(f[cc*8+jj]);
        const int c16 = half * 4 + cc;
        *(short8*)(lds + 32768 + colL * 128 + ((c16 ^ (colL & 7)) << 4)) = o8;
      }
    }
    {
      short8 z8;
      #pragma unroll
      for (int jj = 0; jj < 8; ++jj) z8[jj] = 0;
      if (half == 0) {
        const float4v* src = (const float4v*)(W_e + (size_t)col * DIN + 64);
        float g2[16];
        #pragma unroll
        for (int i = 0; i < 4; ++i) {
          const float4v t4 = src[i];
          g2[i*4+0]=t4[0]; g2[i*4+1]=t4[1]; g2[i*4+2]=t4[2]; g2[i*4+3]=t4[3];
        }
        #pragma unroll
        for (int cc = 0; cc < 2; ++cc) {
          short8 o8;
          #pragma unroll
          for (int jj = 0; jj < 8; ++jj) o8[jj] = (short)f2bf(g2[cc*8+jj]);
          *(short8*)(lds + 98304 + colL * 128 + ((cc ^ (colL & 7)) << 4)) = o8;
        }
        #pragma unroll
        for (int cc = 2; cc < 4; ++cc)
          *(short8*)(lds + 98304 + colL * 128 + ((cc ^ (colL & 7)) << 4)) = z8;
      } else {
        #pragma unroll
        for (int cc = 4; cc < 8; ++cc)
          *(short8*)(lds + 98304 + colL * 128 + ((cc ^ (colL & 7)) << 4)) = z8;
      }
    }
  }
  __syncthreads();

  f32x4 acc[8][4];
  #pragma unroll
  for (int m = 0; m < 8; ++m)
    #pragma unroll
    for (int n = 0; n < 4; ++n) acc[m][n] = f32x4{0.f, 0.f, 0.f, 0.f};

  #pragma unroll
  for (int q = 0; q < 2; ++q) {
    const unsigned char* bufp = lds + q * 65536;
    short8 bfr[4][2];
    #pragma unroll
    for (int n = 0; n < 4; ++n) {
      const int col = wc * 64 + n * 16 + cl;
      #pragma unroll
      for (int ks = 0; ks < 2; ++ks)
        bfr[n][ks] = *(const short8*)(bufp + 32768 + col * 128 +
                                      ((((ks << 2) + kgrp) ^ (col & 7)) << 4));
    }
    #pragma unroll
    for (int g = 0; g < 4; ++g) {
      short8 af[2][2];
      #pragma unroll
      for (int mm = 0; mm < 2; ++mm) {
        const int row = wr * 128 + (g * 2 + mm) * 16 + cl;
        #pragma unroll
        for (int ks = 0; ks < 2; ++ks)
          af[mm][ks] = *(const short8*)(bufp + row * 128 +
                                        ((((ks << 2) + kgrp) ^ (row & 7)) << 4));
      }
      #pragma unroll
      for (int ks = 0; ks < 2; ++ks)
        #pragma unroll
        for (int mm = 0; mm < 2; ++mm)
          #pragma unroll
          for (int n = 0; n < 4; ++n)
            acc[g * 2 + mm][n] = __builtin_amdgcn_mfma_f32_16x16x32_bf16(
                af[mm][ks], bfr[n][ks], acc[g * 2 + mm][n], 0, 0, 0);
    }
  }

  #pragma unroll
  for (int m = 0; m < 8; ++m) {
    #pragma unroll
    for (int n = 0; n < 4; ++n) {
      const int gc = col0 + wc * 64 + n * 16 + cl;
      const float be = b_e[gc];
      #pragma unroll
      for (int e2 = 0; e2 < 4; ++e2) {
        const int gr = row0 + wr * 128 + m * 16 + rg + e2;
        u[(size_t)gr * H_ + gc] = f2bf(fmaxf(acc[m][n][e2] + be, 0.f));
      }
    }
  }
}

// ---------------------------------------------------------------------------
// Kernel 2: B-projection GEMM — TRIPLE-BUFFERED ring, ONE barrier per K-tile.
// BM=BN=256, BK=32, NT=16; 96KB LDS = 3 x (A 16KB + B 16KB). Per tile t:
//   stage(t+2) -> buf[(t+2)%3]        (never the buffer being read: %3 ring)
//   12 ds_read_b128 (af x8, bfr x4) from buf[t%3]
//   lgkmcnt(0); setprio'd 32 MFMA
//   vmcnt(4)  -> stage(t+1) resident (its 4 loads older than t+2's 4)
//   ONE s_barrier
// Safety: reads of buf[t%3] covered by vmcnt(4)@t-1 + barrier; stage(t+2)
// writes buf[(t-1)%3], whose reads ended before the t-1 barrier; fast waves
// issue their next stage only after the shared barrier. vmcnt slack = two
// full tile-times (stage issued 2 tiles before its wait) -> expected 0 wait.
// Swizzle: 64B rows, c16 in {0..3}, XOR (row>>1)&3 (R11-verified), applied
// to pre-swizzled global source AND ds_read address (both-sides, rule #21).
// CE epilogue identical to R16 (constants preloaded under prologue staging).
// ---------------------------------------------------------------------------
__global__ __launch_bounds__(512) void gemm_bproj(
    const unsigned short* __restrict__ A, const unsigned short* __restrict__ Bt,
    unsigned short* __restrict__ Cb,
    const float* __restrict__ powa, float* __restrict__ e)
{
  constexpr int NT = 16;                 // K = 512 / 32
  constexpr int ABYTES = 256 * 32 * 2;   // 16384
  constexpr int BUF = 2 * ABYTES;        // 32768 (A + B)
  __shared__ __align__(16) unsigned char lds[3 * BUF];   // 96 KB

  const int tid  = threadIdx.x;
  const int lane = tid & 63;
  const int wid  = tid >> 6;
  const int wr   = wid >> 2;             // 0..1 (M)
  const int wc   = wid & 3;              // 0..3 (N)
  const int cl   = lane & 15;
  const int kgrp = lane >> 4;
  const int rg   = kgrp * 4;

  const int X  = (int)blockIdx.x & 7;
  const int j  = (int)blockIdx.x >> 3;
  const int mt = X * 16 + (j >> 1);
  const int nt = j & 1;
  const int row0 = mt * 256, col0 = nt * 256;

  // stage one K-tile (A 16KB: 2 rounds; B 16KB: 2 rounds) = 4 loads/thread
  auto stage = [&](int q, int buf) {
    const int k0 = q * 32;
    #pragma unroll
    for (int r = 0; r < 2; ++r) {
      const int o   = r * 8192 + tid * 16;     // [0,16384)
      const int row = o >> 6;                  // 64B rows
      const int c16 = (o >> 4) & 3;
      const int kk  = (c16 ^ ((row >> 1) & 3)) << 3;
      __builtin_amdgcn_global_load_lds(
          (const __attribute__((address_space(1))) void*)
              (A + (size_t)(row0 + row) * H_ + k0 + kk),
          (__attribute__((address_space(3))) void*)(lds + buf * BUF + o),
          16, 0, 0);
    }
    #pragma unroll
    for (int r = 0; r < 2; ++r) {
      const int o   = r * 8192 + tid * 16;
      const int col = o >> 6;
      const int c16 = (o >> 4) & 3;
      const int kk  = (c16 ^ ((col >> 1) & 3)) << 3;
      __builtin_amdgcn_global_load_lds(
          (const __attribute__((address_space(1))) void*)
              (Bt + (size_t)(col0 + col) * H_ + k0 + kk),
          (__attribute__((address_space(3))) void*)(lds + buf * BUF + ABYTES + o),
          16, 0, 0);
    }
  };

  f32x4 acc[8][4];
  #pragma unroll
  for (int m = 0; m < 8; ++m)
    #pragma unroll
    for (int n = 0; n < 4; ++n) acc[m][n] = f32x4{0.f, 0.f, 0.f, 0.f};

  stage(0, 0);
  stage(1, 1);

  // CE-epilogue constant preload (latency hidden under staging wait)
  float a16r[4], wkr[4][4];
  #pragma unroll
  for (int n = 0; n < 4; ++n) {
    const int h = col0 + wc * 64 + n * 16 + cl;
    a16r[n] = powa[15 * H_ + h];
    #pragma unroll
    for (int e2 = 0; e2 < 4; ++e2) {
      const int k = 15 - rg - e2;
      wkr[n][e2] = (k == 0) ? 1.f : powa[(size_t)(k - 1) * H_ + h];
    }
  }

  asm volatile("s_waitcnt vmcnt(4)" ::: "memory");   // tile 0 resident
  __builtin_amdgcn_sched_barrier(0);
  __builtin_amdgcn_s_barrier();

  for (int t = 0; t < NT; ++t) {
    const unsigned char* bufp = lds + (t % 3) * BUF;

    if (t + 2 < NT) stage(t + 2, (t + 2) % 3);

    short8 bfr[4];
    #pragma unroll
    for (int n = 0; n < 4; ++n) {
      const int col = wc * 64 + n * 16 + cl;
      bfr[n] = *(const short8*)(bufp + ABYTES + col * 64 +
                                ((kgrp ^ ((col >> 1) & 3)) << 4));
    }
    short8 af[8];
    #pragma unroll
    for (int m = 0; m < 8; ++m) {
      const int row = wr * 128 + m * 16 + cl;
      af[m] = *(const short8*)(bufp + row * 64 +
                               ((kgrp ^ ((row >> 1) & 3)) << 4));
    }
    asm volatile("s_waitcnt lgkmcnt(0)" ::: "memory");
    __builtin_amdgcn_sched_barrier(0);

    __builtin_amdgcn_s_setprio(1);
    #pragma unroll
    for (int m = 0; m < 8; ++m)
      #pragma unroll
      for (int n = 0; n < 4; ++n)
        acc[m][n] = __builtin_amdgcn_mfma_f32_16x16x32_bf16(
            af[m], bfr[n], acc[m][n], 0, 0, 0);
    __builtin_amdgcn_s_setprio(0);

    if (t + 2 < NT) {
      asm volatile("s_waitcnt vmcnt(4)" ::: "memory");   // tile t+1 resident
    } else if (t + 1 < NT) {
      asm volatile("s_waitcnt vmcnt(0)" ::: "memory");
    }
    __builtin_amdgcn_sched_barrier(0);
    __builtin_amdgcn_s_barrier();                        // the ONLY barrier
  }

  // Epilogue: v write. D[r][c]: c = lane&15, r = (lane>>4)*4 + e2
  #pragma unroll
  for (int m = 0; m < 8; ++m) {
    #pragma unroll
    for (int n = 0; n < 4; ++n) {
      const int gc = col0 + wc * 64 + n * 16 + cl;
      #pragma unroll
      for (int e2 = 0; e2 < 4; ++e2) {
        const int gr = row0 + wr * 128 + m * 16 + rg + e2;
        Cb[(size_t)gr * H_ + gc] = f2bf(acc[m][n][e2]);
      }
    }
  }

  // Chunk-end e: wave spans 2 chunks (m 0..3, m 4..7); constants preloaded.
  #pragma unroll
  for (int c = 0; c < 2; ++c) {
    const int chunk = ((row0 + wr * 128) >> 6) + c;
    #pragma unroll
    for (int n = 0; n < 4; ++n) {
      const int h = col0 + wc * 64 + n * 16 + cl;
      const float a16 = a16r[n];
      float ep = 0.f;
      #pragma unroll
      for (int e2 = 0; e2 < 4; ++e2) {
        float hsum = acc[c * 4 + 0][n][e2];
        hsum = fmaf(hsum, a16, acc[c * 4 + 1][n][e2]);
        hsum = fmaf(hsum, a16, acc[c * 4 + 2][n][e2]);
        hsum = fmaf(hsum, a16, acc[c * 4 + 3][n][e2]);
        ep = fmaf(wkr[n][e2], hsum, ep);
      }
      ep += __shfl_xor(ep, 16);
      ep += __shfl_xor(ep, 32);
      if (kgrp == 0)
        e[(size_t)chunk * H_ + h] = ep;
    }
  }
}

// ---------------------------------------------------------------------------
// Kernel 3: fused carry + scan + out-projection (R12-proven, unchanged;
// chunk map matches producer XCDs: chunk = (bid&7)*64 + bid>>3).
// ---------------------------------------------------------------------------
__global__ __launch_bounds__(256) void scan_out(
    const unsigned int* __restrict__ v, const float* __restrict__ e,
    const float* __restrict__ aarr, const unsigned short* __restrict__ Wo,
    const float* __restrict__ b_out, float* __restrict__ y)
{
  __shared__ __align__(16) unsigned char sbytes[64 * 1024];
  const int blk = ((int)blockIdx.x & 7) * 64 + ((int)blockIdx.x >> 3);
  const int b = blk >> 5, c = blk & 31;
  const int tid = threadIdx.x;
  const int lane = tid & 63, w = tid >> 6;
  const int row_base = blk * L_;

  {
    const int h0 = tid * 2;
    const float a0 = aarr[h0], a1 = aarr[h0 + 1];
    float aL0 = a0 * a0, aL1 = a1 * a1;
    aL0 *= aL0; aL1 *= aL1;
    aL0 *= aL0; aL1 *= aL1;
    aL0 *= aL0; aL1 *= aL1;
    aL0 *= aL0; aL1 *= aL1;
    aL0 *= aL0; aL1 *= aL1;                       // a^64
    float s0 = 0.f, s1 = 0.f;
    #pragma unroll
    for (int g = 0; g < 4; ++g) {
      float ev0[8], ev1[8];
      #pragma unroll
      for (int k = 0; k < 8; ++k) {
        const size_t o = ((size_t)(b * C_ + g * 8 + k)) * H_ + h0;
        ev0[k] = e[o]; ev1[k] = e[o + 1];
      }
      #pragma unroll
      for (int k = 0; k < 8; ++k) {
        const bool pred = (g * 8 + k) < c;
        s0 = pred ? fmaf(aL0, s0, ev0[k]) : s0;
        s1 = pred ? fmaf(aL1, s1, ev1[k]) : s1;
      }
    }
    const unsigned int* vp = v + (size_t)row_base * (H_ / 2) + tid;
    #pragma unroll 8
    for (int t = 0; t < L_; ++t) {
      const unsigned int pv = vp[(size_t)t * (H_ / 2)];
      s0 = fmaf(a0, s0, bf2f((unsigned short)(pv & 0xffff)));
      s1 = fmaf(a1, s1, bf2f((unsigned short)(pv >> 16)));
      const int byte = t * 1024 + ((tid * 4) ^ ((t & 7) << 4));
      *(unsigned int*)(sbytes + byte) =
          (unsigned int)f2bf(s0) | ((unsigned int)f2bf(s1) << 16);
    }
  }
  __syncthreads();

  f32x4 acc[4];
  #pragma unroll
  for (int n = 0; n < 4; ++n) acc[n] = f32x4{0.f, 0.f, 0.f, 0.f};
  const int r = w * 16 + (lane & 15);
  const int kof = (lane >> 4) * 8;
  #pragma unroll 4
  for (int k0 = 0; k0 < H_; k0 += 32) {
    const int byte = r * 1024 + (((k0 + kof) * 2) ^ ((r & 7) << 4));
    const short8 af = *(const short8*)(sbytes + byte);
    #pragma unroll
    for (int n = 0; n < 4; ++n) {
      const short8 bf = *(const short8*)(Wo + (size_t)(n * 16 + (lane & 15)) * H_ + k0 + kof);
      acc[n] = __builtin_amdgcn_mfma_f32_16x16x32_bf16(af, bf, acc[n], 0, 0, 0);
    }
  }
  const int cl = lane & 15, rg = (lane >> 4) * 4;
  #pragma unroll
  for (int n = 0; n < 4; ++n) {
    #pragma unroll
    for (int e2 = 0; e2 < 4; ++e2) {
      const int gr = row_base + w * 16 + rg + e2;
      const int gc = n * 16 + cl;
      y[(size_t)gr * O_ + gc] = acc[n][e2] + b_out[gc];
    }
  }
}

// ---------------------------------------------------------------------------
extern "C" void kernel_launch(void* const* d_in, const int* in_sizes, int n_in,
                              void* d_out, int out_size, void* d_ws, size_t ws_size,
                              hipStream_t stream)
{
  const float* obs   = (const float*)d_in[0];
  const float* act   = (const float*)d_in[1];
  const float* W_e   = (const float*)d_in[2];
  const float* b_e   = (const float*)d_in[3];
  const float* a_raw = (const float*)d_in[4];
  const float* W_B   = (const float*)d_in[5];
  const float* W_out = (const float*)d_in[6];
  const float* b_out = (const float*)d_in[7];
  float* y = (float*)d_out;

  char* w = (char*)d_ws;
  auto carve = [&](size_t bytes) {
    char* p = w; w += (bytes + 255) & ~(size_t)255; return p;
  };
  unsigned short* WBb   = (unsigned short*)carve((size_t)H_ * H_ * 2);
  unsigned short* Woutb = (unsigned short*)carve((size_t)O_ * H_ * 2);
  float*          aarr  = (float*)carve((size_t)H_ * 4);
  float*          powa  = (float*)carve((size_t)16 * H_ * 4);
  unsigned short* u     = (unsigned short*)carve((size_t)BT_ * H_ * 2);   // 33.5 MB
  unsigned short* v     = (unsigned short*)carve((size_t)BT_ * H_ * 2);   // 33.5 MB
  float*          e     = (float*)carve((size_t)NCHUNK * H_ * 4);         // 1 MB

  // 1) embed (+ inline weight prep) -> u
  embed_gemm<<<256, 512, 0, stream>>>(obs, act, W_e, b_e, a_raw, W_B, W_out,
                                      WBb, Woutb, aarr, powa, u);
  // 2) v = u @ WB^T (triple-buffered ring, 1 barrier/K-tile); emits e
  gemm_bproj<<<256, 512, 0, stream>>>(u, WBb, v, powa, e);
  // 3) fused carry + scan + out-projection -> y
  scan_out<<<NCHUNK, 256, 0, stream>>>((const unsigned int*)v, e, aarr,
                                       Woutb, b_out, y);
}